// Round 1
// baseline (2042.683 us; speedup 1.0000x reference)
//
#include <hip/hip_runtime.h>
#include <cstdint>
#include <cstddef>

#define NN 50000
#define EE 800000
#define ET (EE + NN)
#define GG 64
#define HH 4
#define RSQ 0.9999950000374997f   // 1/sqrt(1+1e-5)

// ---------------------------------------------------------------- utilities

static inline void* carve(char*& p, size_t bytes) {
    void* r = (void*)p;
    p += (bytes + 255) & ~(size_t)255;
    return r;
}

// ------------------------------------------------------------- CSR building

__global__ void edge_accum_kernel(const int* __restrict__ dst0,
                                  const float* __restrict__ ef,
                                  int* __restrict__ deg,
                                  float* __restrict__ esum) {
    int e = blockIdx.x * blockDim.x + threadIdx.x;
    if (e >= EE) return;
    int d = dst0[e];
    atomicAdd(&deg[d], 1);
#pragma unroll
    for (int k = 0; k < 6; k++)
        atomicAdd(&esum[(size_t)d * 6 + k], ef[(size_t)e * 6 + k]);
}

__global__ void emean_kernel(const int* __restrict__ deg, float* __restrict__ esum) {
    int n = blockIdx.x * blockDim.x + threadIdx.x;
    if (n >= NN) return;
    float inv = 1.0f / fmaxf((float)deg[n], 1.0f);
#pragma unroll
    for (int k = 0; k < 6; k++) esum[(size_t)n * 6 + k] *= inv;
}

#define SCAN_B 512
__global__ void scan1_kernel(const int* __restrict__ deg, int* __restrict__ out,
                             int* __restrict__ bsum, int n) {
    __shared__ int tmp[SCAN_B];
    int i = blockIdx.x * SCAN_B + threadIdx.x;
    int v = (i < n) ? (deg[i] + 1) : 0;   // +1 self loop
    tmp[threadIdx.x] = v;
    __syncthreads();
    for (int off = 1; off < SCAN_B; off <<= 1) {
        int t = (threadIdx.x >= off) ? tmp[threadIdx.x - off] : 0;
        __syncthreads();
        tmp[threadIdx.x] += t;
        __syncthreads();
    }
    if (i < n) out[i] = tmp[threadIdx.x] - v;       // exclusive
    if (threadIdx.x == SCAN_B - 1) bsum[blockIdx.x] = tmp[threadIdx.x];
}

__global__ void scan2_kernel(int* __restrict__ bsum, int nb) {
    __shared__ int tmp[128];
    int v = (threadIdx.x < nb) ? bsum[threadIdx.x] : 0;
    tmp[threadIdx.x] = v;
    __syncthreads();
    for (int off = 1; off < 128; off <<= 1) {
        int t = (threadIdx.x >= off) ? tmp[threadIdx.x - off] : 0;
        __syncthreads();
        tmp[threadIdx.x] += t;
        __syncthreads();
    }
    if (threadIdx.x < nb) bsum[threadIdx.x] = tmp[threadIdx.x] - v;  // exclusive
}

__global__ void scan3_kernel(int* __restrict__ out, const int* __restrict__ bsum, int n) {
    int i = blockIdx.x * SCAN_B + threadIdx.x;
    if (i < n) out[i] += bsum[blockIdx.x];
}

__global__ void set_total_kernel(int* __restrict__ row_ptr) {
    if (threadIdx.x == 0) row_ptr[NN] = ET;
}

__global__ void fill_edges_kernel(const int* __restrict__ src0, const int* __restrict__ dst0,
                                  const int* __restrict__ row_ptr, int* __restrict__ cursor,
                                  int* __restrict__ ssrc, int* __restrict__ seid) {
    int e = blockIdx.x * blockDim.x + threadIdx.x;
    if (e >= EE) return;
    int d = dst0[e];
    int pos = atomicAdd(&cursor[d], 1);
    int idx = row_ptr[d] + pos;
    ssrc[idx] = src0[e];
    seid[idx] = e;
}

__global__ void fill_loops_kernel(const int* __restrict__ row_ptr, int* __restrict__ cursor,
                                  int* __restrict__ ssrc, int* __restrict__ seid) {
    int n = blockIdx.x * blockDim.x + threadIdx.x;
    if (n >= NN) return;
    int pos = atomicAdd(&cursor[n], 1);
    int idx = row_ptr[n] + pos;
    ssrc[idx] = n;
    seid[idx] = EE + n;
}

// --------------------------------------------------------------------- GEMM
// C[M,Nc] = A[M,K] @ B[K,Nc]; fp32, 64x64 tile, BK=16, 256 threads, 4x4 micro.

#define BM 64
#define BN 64
#define BK 16
__global__ __launch_bounds__(256) void gemm_kernel(const float* __restrict__ A,
                                                   const float* __restrict__ B,
                                                   float* __restrict__ C,
                                                   int M, int K, int Nc) {
    __shared__ float As[BK][BM + 4];
    __shared__ float Bs[BK][BN + 4];
    const int tid = threadIdx.x;
    const int bm = blockIdx.x * BM;
    const int bn = blockIdx.y * BN;
    const int tr = tid >> 4;          // 0..15
    const int tc = tid & 15;          // 0..15
    const int la_r = tid >> 2;        // 0..63
    const int la_c = (tid & 3) * 4;   // {0,4,8,12}
    const int lb_r = tid >> 4;        // 0..15
    const int lb_c = (tid & 15) * 4;  // {0..60}
    float acc[4][4] = {{0.f}};

    for (int k0 = 0; k0 < K; k0 += BK) {
        float4 av = make_float4(0.f, 0.f, 0.f, 0.f);
        int arow = bm + la_r;
        if (arow < M) av = *(const float4*)&A[(size_t)arow * K + k0 + la_c];
        As[la_c + 0][la_r] = av.x;
        As[la_c + 1][la_r] = av.y;
        As[la_c + 2][la_r] = av.z;
        As[la_c + 3][la_r] = av.w;
        float4 bv = *(const float4*)&B[(size_t)(k0 + lb_r) * Nc + bn + lb_c];
        *(float4*)&Bs[lb_r][lb_c] = bv;
        __syncthreads();
#pragma unroll
        for (int kk = 0; kk < BK; kk++) {
            float4 a4 = *(const float4*)&As[kk][tr * 4];
            float4 b4 = *(const float4*)&Bs[kk][tc * 4];
            float ax[4] = {a4.x, a4.y, a4.z, a4.w};
            float bx[4] = {b4.x, b4.y, b4.z, b4.w};
#pragma unroll
            for (int i = 0; i < 4; i++)
#pragma unroll
                for (int j = 0; j < 4; j++) acc[i][j] += ax[i] * bx[j];
        }
        __syncthreads();
    }
#pragma unroll
    for (int i = 0; i < 4; i++) {
        int row = bm + tr * 4 + i;
        if (row < M) {
            float4 o = make_float4(acc[i][0], acc[i][1], acc[i][2], acc[i][3]);
            *(float4*)&C[(size_t)row * Nc + bn + tc * 4] = o;
        }
    }
}

// --------------------------------------------------- per-node attention dots
// al_s[n,h] = sum_c xs[n,h,c]*a_s[h,c]; one wave per node.

template <int C_>
__global__ __launch_bounds__(256) void attn_node_kernel(const float* __restrict__ xs,
                                                        const float* __restrict__ a_s,
                                                        const float* __restrict__ a_d,
                                                        float* __restrict__ al_s,
                                                        float* __restrict__ al_d) {
    constexpr int HC = HH * C_;
    constexpr int NK = HC / 64;
    int wid = (blockIdx.x * blockDim.x + threadIdx.x) >> 6;
    int lane = threadIdx.x & 63;
    if (wid >= NN) return;
    const float* row = xs + (size_t)wid * HC;
    float ss[HH] = {0.f, 0.f, 0.f, 0.f};
    float sd[HH] = {0.f, 0.f, 0.f, 0.f};
#pragma unroll
    for (int k = 0; k < NK; k++) {
        int idx = (k << 6) + lane;
        float v = row[idx];
        float ps = v * a_s[idx];
        float pd = v * a_d[idx];
#pragma unroll
        for (int off = 32; off; off >>= 1) {
            ps += __shfl_xor(ps, off);
            pd += __shfl_xor(pd, off);
        }
        constexpr int dummy = 0; (void)dummy;
        ss[(k * 64) / C_] += ps;
        sd[(k * 64) / C_] += pd;
    }
    if (lane == 0) {
#pragma unroll
        for (int h = 0; h < HH; h++) {
            al_s[(size_t)wid * HH + h] = ss[h];
            al_d[(size_t)wid * HH + h] = sd[h];
        }
    }
}

// ------------------------------------------------------------- edge logits

__global__ void wea_kernel(const float* __restrict__ We, const float* __restrict__ ae,
                           float* __restrict__ Wea, int HC, int C) {
    int t = threadIdx.x;
    if (t >= 24) return;
    int k = t / 4, h = t % 4;
    float s = 0.f;
    for (int c = 0; c < C; c++) s += We[(size_t)k * HC + h * C + c] * ae[(size_t)h * C + c];
    Wea[k * 4 + h] = s;
}

__global__ void edge_al_kernel(const int* __restrict__ src0, const int* __restrict__ dst0,
                               const float* __restrict__ ef, const float* __restrict__ emean,
                               const float* __restrict__ Wea,
                               const float* __restrict__ al_s, const float* __restrict__ al_d,
                               float* __restrict__ al) {
    int e = blockIdx.x * blockDim.x + threadIdx.x;
    if (e >= ET) return;
    int s, d;
    float ev[6];
    if (e < EE) {
        s = src0[e];
        d = dst0[e];
#pragma unroll
        for (int k = 0; k < 6; k++) ev[k] = ef[(size_t)e * 6 + k];
    } else {
        s = d = e - EE;
#pragma unroll
        for (int k = 0; k < 6; k++) ev[k] = emean[(size_t)s * 6 + k];
    }
    float4 as4 = *(const float4*)&al_s[(size_t)s * 4];
    float4 ad4 = *(const float4*)&al_d[(size_t)d * 4];
    float asv[4] = {as4.x, as4.y, as4.z, as4.w};
    float adv[4] = {ad4.x, ad4.y, ad4.z, ad4.w};
    float o[4];
#pragma unroll
    for (int h = 0; h < 4; h++) {
        float v = asv[h] + adv[h];
#pragma unroll
        for (int k = 0; k < 6; k++) v += ev[k] * Wea[k * 4 + h];
        o[h] = v > 0.f ? v : 0.2f * v;
    }
    *(float4*)&al[(size_t)e * 4] = make_float4(o[0], o[1], o[2], o[3]);
}

// --------------------------------------------- per-dst softmax (in-place w)

__global__ void softmax_stats_kernel(const int* __restrict__ row_ptr,
                                     const int* __restrict__ seid,
                                     float* __restrict__ al) {
    int n = blockIdx.x * blockDim.x + threadIdx.x;
    if (n >= NN) return;
    int b = row_ptr[n], e = row_ptr[n + 1];
    float m[4] = {-1e30f, -1e30f, -1e30f, -1e30f};
    for (int i = b; i < e; i++) {
        float4 v = *(const float4*)&al[(size_t)seid[i] * 4];
        m[0] = fmaxf(m[0], v.x);
        m[1] = fmaxf(m[1], v.y);
        m[2] = fmaxf(m[2], v.z);
        m[3] = fmaxf(m[3], v.w);
    }
    float s[4] = {0.f, 0.f, 0.f, 0.f};
    for (int i = b; i < e; i++) {
        float4 v = *(const float4*)&al[(size_t)seid[i] * 4];
        s[0] += __expf(v.x - m[0]);
        s[1] += __expf(v.y - m[1]);
        s[2] += __expf(v.z - m[2]);
        s[3] += __expf(v.w - m[3]);
    }
    float r[4];
#pragma unroll
    for (int h = 0; h < 4; h++) r[h] = 1.0f / (s[h] + 1e-16f);
    for (int i = b; i < e; i++) {
        size_t o = (size_t)seid[i] * 4;
        float4 v = *(const float4*)&al[o];
        v.x = __expf(v.x - m[0]) * r[0];
        v.y = __expf(v.y - m[1]) * r[1];
        v.z = __expf(v.z - m[2]) * r[2];
        v.w = __expf(v.w - m[3]) * r[3];
        *(float4*)&al[o] = v;
    }
}

// ------------------------------------------- aggregation + bias + BN + ELU

template <int C_>
__global__ __launch_bounds__(256) void aggregate_kernel(const float* __restrict__ xs,
                                                        const float* __restrict__ w,
                                                        const int* __restrict__ row_ptr,
                                                        const int* __restrict__ ssrc,
                                                        const int* __restrict__ seid,
                                                        const float* __restrict__ bias,
                                                        const float* __restrict__ gam,
                                                        const float* __restrict__ bet,
                                                        float* __restrict__ hout) {
    constexpr int HC = HH * C_;
    constexpr int NK = HC / 64;
    int wid = (blockIdx.x * blockDim.x + threadIdx.x) >> 6;
    int lane = threadIdx.x & 63;
    if (wid >= NN) return;
    int b = row_ptr[wid], e = row_ptr[wid + 1];
    float acc[NK];
#pragma unroll
    for (int k = 0; k < NK; k++) acc[k] = 0.f;
    for (int i = b; i < e; i++) {
        int s = ssrc[i];
        int eid = seid[i];
        float4 w4 = *(const float4*)&w[(size_t)eid * 4];
        float wv[4] = {w4.x, w4.y, w4.z, w4.w};
        const float* row = xs + (size_t)s * HC;
#pragma unroll
        for (int k = 0; k < NK; k++) acc[k] += wv[(k * 64) / C_] * row[(k << 6) + lane];
    }
#pragma unroll
    for (int k = 0; k < NK; k++) {
        int idx = (k << 6) + lane;
        float v = acc[k] + bias[idx];
        v = gam[idx] * v * RSQ + bet[idx];
        hout[(size_t)wid * HC + idx] = v > 0.f ? v : (__expf(v) - 1.0f);
    }
}

// ----------------------------------------------------------- pooling + head

__global__ void cnt_kernel(const int* __restrict__ batch, float* __restrict__ cnt) {
    int n = blockIdx.x * blockDim.x + threadIdx.x;
    if (n >= NN) return;
    atomicAdd(&cnt[batch[n]], 1.0f);
}

__global__ void pool_kernel(const float* __restrict__ h3, const int* __restrict__ batch,
                            float* __restrict__ pooled) {
    size_t idx = (size_t)blockIdx.x * blockDim.x + threadIdx.x;
    if (idx >= (size_t)NN * 256) return;
    int n = (int)(idx >> 8);
    int c = (int)(idx & 255);
    atomicAdd(&pooled[(size_t)batch[n] * 256 + c], h3[idx]);
}

__global__ void final_kernel(const float* __restrict__ pooled, const float* __restrict__ cnt,
                             const float* __restrict__ Wf1, const float* __restrict__ bf1,
                             const float* __restrict__ gf, const float* __restrict__ bbf,
                             const float* __restrict__ Wf2, const float* __restrict__ bf2,
                             float* __restrict__ out) {
    int g = blockIdx.x;
    int j = threadIdx.x;  // 32 threads
    __shared__ float hh[32];
    float c = fmaxf(cnt[g], 1.0f);
    float inv = 1.0f / c;
    float acc = bf1[j];
    for (int i = 0; i < 256; i++) acc += (pooled[(size_t)g * 256 + i] * inv) * Wf1[(size_t)i * 32 + j];
    float v = gf[j] * acc * RSQ + bbf[j];
    hh[j] = v > 0.f ? v : (__expf(v) - 1.0f);
    __syncthreads();
    if (j == 0) {
        float l0 = bf2[0], l1 = bf2[1];
        for (int i = 0; i < 32; i++) {
            l0 += hh[i] * Wf2[i * 2 + 0];
            l1 += hh[i] * Wf2[i * 2 + 1];
        }
        float mx = fmaxf(l0, l1);
        float lse = mx + logf(__expf(l0 - mx) + __expf(l1 - mx));
        out[g * 2 + 0] = l0 - lse;
        out[g * 2 + 1] = l1 - lse;
    }
}

// -------------------------------------------------------------------- launch

extern "C" void kernel_launch(void* const* d_in, const int* in_sizes, int n_in,
                              void* d_out, int out_size, void* d_ws, size_t ws_size,
                              hipStream_t stream) {
    (void)in_sizes; (void)n_in; (void)out_size; (void)ws_size;

    const float* x  = (const float*)d_in[0];
    const float* ef = (const float*)d_in[1];
    const float* W_[3]  = {(const float*)d_in[2],  (const float*)d_in[10], (const float*)d_in[18]};
    const float* We_[3] = {(const float*)d_in[3],  (const float*)d_in[11], (const float*)d_in[19]};
    const float* As_[3] = {(const float*)d_in[4],  (const float*)d_in[12], (const float*)d_in[20]};
    const float* Ad_[3] = {(const float*)d_in[5],  (const float*)d_in[13], (const float*)d_in[21]};
    const float* Ae_[3] = {(const float*)d_in[6],  (const float*)d_in[14], (const float*)d_in[22]};
    const float* Bi_[3] = {(const float*)d_in[7],  (const float*)d_in[15], (const float*)d_in[23]};
    const float* Ga_[3] = {(const float*)d_in[8],  (const float*)d_in[16], (const float*)d_in[24]};
    const float* Be_[3] = {(const float*)d_in[9],  (const float*)d_in[17], (const float*)d_in[25]};
    const float* Wf1 = (const float*)d_in[26];
    const float* bf1 = (const float*)d_in[27];
    const float* gf  = (const float*)d_in[28];
    const float* bbf = (const float*)d_in[29];
    const float* Wf2 = (const float*)d_in[30];
    const float* bf2 = (const float*)d_in[31];
    const int* eidx  = (const int*)d_in[32];
    const int* src0  = eidx;
    const int* dst0  = eidx + EE;
    const int* batch = (const int*)d_in[33];
    float* out = (float*)d_out;

    char* p = (char*)d_ws;
    float* bufA   = (float*)carve(p, (size_t)NN * 512 * 4);
    float* bufB   = (float*)carve(p, (size_t)NN * 512 * 4);
    float* al     = (float*)carve(p, (size_t)ET * 4 * 4);
    float* als    = (float*)carve(p, (size_t)NN * 4 * 4);
    float* ald    = (float*)carve(p, (size_t)NN * 4 * 4);
    float* emean  = (float*)carve(p, (size_t)NN * 6 * 4);
    float* wea    = (float*)carve(p, 256);
    float* pooled = (float*)carve(p, (size_t)GG * 256 * 4);
    float* cnt    = (float*)carve(p, (size_t)GG * 4);
    int* deg    = (int*)carve(p, (size_t)NN * 4);
    int* rowptr = (int*)carve(p, (size_t)(NN + 1) * 4);
    int* cursor = (int*)carve(p, (size_t)NN * 4);
    int* ssrc   = (int*)carve(p, (size_t)ET * 4);
    int* seid   = (int*)carve(p, (size_t)ET * 4);
    int* bsum   = (int*)carve(p, 512);

    // zero-init accumulators
    hipMemsetAsync(deg, 0, (size_t)NN * 4, stream);
    hipMemsetAsync(emean, 0, (size_t)NN * 6 * 4, stream);
    hipMemsetAsync(cursor, 0, (size_t)NN * 4, stream);
    hipMemsetAsync(pooled, 0, (size_t)GG * 256 * 4, stream);
    hipMemsetAsync(cnt, 0, (size_t)GG * 4, stream);

    // degree + edge-feature sums, then mean
    edge_accum_kernel<<<(EE + 255) / 256, 256, 0, stream>>>(dst0, ef, deg, emean);
    emean_kernel<<<(NN + 255) / 256, 256, 0, stream>>>(deg, emean);

    // CSR by dst (counts = deg+1 for self loop)
    int nb = (NN + SCAN_B - 1) / SCAN_B;  // 98
    scan1_kernel<<<nb, SCAN_B, 0, stream>>>(deg, rowptr, bsum, NN);
    scan2_kernel<<<1, 128, 0, stream>>>(bsum, nb);
    scan3_kernel<<<nb, SCAN_B, 0, stream>>>(rowptr, bsum, NN);
    set_total_kernel<<<1, 64, 0, stream>>>(rowptr);
    fill_edges_kernel<<<(EE + 255) / 256, 256, 0, stream>>>(src0, dst0, rowptr, cursor, ssrc, seid);
    fill_loops_kernel<<<(NN + 255) / 256, 256, 0, stream>>>(rowptr, cursor, ssrc, seid);

    const int fin[3] = {32, 256, 512};
    const int HCs[3] = {256, 512, 256};
    const int Cs[3]  = {64, 128, 64};
    const float* hin = x;

    for (int li = 0; li < 3; li++) {
        int K = fin[li], HC = HCs[li];
        dim3 gg((NN + BM - 1) / BM, HC / BN);
        gemm_kernel<<<gg, 256, 0, stream>>>(hin, W_[li], bufB, NN, K, HC);

        int wblocks = (NN * 64 + 255) / 256;
        if (Cs[li] == 64)
            attn_node_kernel<64><<<wblocks, 256, 0, stream>>>(bufB, As_[li], Ad_[li], als, ald);
        else
            attn_node_kernel<128><<<wblocks, 256, 0, stream>>>(bufB, As_[li], Ad_[li], als, ald);

        wea_kernel<<<1, 32, 0, stream>>>(We_[li], Ae_[li], wea, HC, Cs[li]);
        edge_al_kernel<<<(ET + 255) / 256, 256, 0, stream>>>(src0, dst0, ef, emean, wea, als, ald, al);
        softmax_stats_kernel<<<(NN + 255) / 256, 256, 0, stream>>>(rowptr, seid, al);

        if (Cs[li] == 64)
            aggregate_kernel<64><<<wblocks, 256, 0, stream>>>(bufB, al, rowptr, ssrc, seid,
                                                              Bi_[li], Ga_[li], Be_[li], bufA);
        else
            aggregate_kernel<128><<<wblocks, 256, 0, stream>>>(bufB, al, rowptr, ssrc, seid,
                                                               Bi_[li], Ga_[li], Be_[li], bufA);
        hin = bufA;
    }

    // mean pool over graphs + head
    cnt_kernel<<<(NN + 255) / 256, 256, 0, stream>>>(batch, cnt);
    pool_kernel<<<(int)(((size_t)NN * 256 + 255) / 256), 256, 0, stream>>>(bufA, batch, pooled);
    final_kernel<<<GG, 32, 0, stream>>>(pooled, cnt, Wf1, bf1, gf, bbf, Wf2, bf2, out);
}

// Round 2
// 1048.730 us; speedup vs baseline: 1.9478x; 1.9478x over previous
//
#include <hip/hip_runtime.h>
#include <cstdint>
#include <cstddef>

#define NN 50000
#define NPAD 50048            // 391 * 128
#define EE 800000
#define ET (EE + NN)
#define GG 64
#define HH 4
#define RSQ 0.9999950000374997f   // 1/sqrt(1+1e-5)

typedef short bf16x8 __attribute__((ext_vector_type(8)));
typedef unsigned short u16x8 __attribute__((ext_vector_type(8)));
typedef float f32x4 __attribute__((ext_vector_type(4)));

__device__ __forceinline__ float bf2f(unsigned short u) {
    union { unsigned int i; float f; } v; v.i = ((unsigned int)u) << 16; return v.f;
}
__device__ __forceinline__ unsigned short f2bf(float f) {
    union { float f; unsigned int i; } v; v.f = f;
    unsigned int u = v.i;
    u += 0x7fffu + ((u >> 16) & 1u);
    return (unsigned short)(u >> 16);
}

static inline void* carve(char*& p, size_t bytes) {
    void* r = (void*)p;
    p += (bytes + 255) & ~(size_t)255;
    return r;
}

// ------------------------------------------------------------- CSR building

__global__ void edge_accum_kernel(const int* __restrict__ dst0,
                                  const float* __restrict__ ef,
                                  int* __restrict__ deg,
                                  float* __restrict__ esum) {
    int e = blockIdx.x * blockDim.x + threadIdx.x;
    if (e >= EE) return;
    int d = dst0[e];
    atomicAdd(&deg[d], 1);
#pragma unroll
    for (int k = 0; k < 6; k++)
        atomicAdd(&esum[(size_t)d * 6 + k], ef[(size_t)e * 6 + k]);
}

__global__ void emean_kernel(const int* __restrict__ deg, float* __restrict__ esum) {
    int n = blockIdx.x * blockDim.x + threadIdx.x;
    if (n >= NN) return;
    float inv = 1.0f / fmaxf((float)deg[n], 1.0f);
#pragma unroll
    for (int k = 0; k < 6; k++) esum[(size_t)n * 6 + k] *= inv;
}

#define SCAN_B 512
__global__ void scan1_kernel(const int* __restrict__ deg, int* __restrict__ out,
                             int* __restrict__ bsum, int n) {
    __shared__ int tmp[SCAN_B];
    int i = blockIdx.x * SCAN_B + threadIdx.x;
    int v = (i < n) ? (deg[i] + 1) : 0;   // +1 self loop
    tmp[threadIdx.x] = v;
    __syncthreads();
    for (int off = 1; off < SCAN_B; off <<= 1) {
        int t = (threadIdx.x >= off) ? tmp[threadIdx.x - off] : 0;
        __syncthreads();
        tmp[threadIdx.x] += t;
        __syncthreads();
    }
    if (i < n) out[i] = tmp[threadIdx.x] - v;       // exclusive
    if (threadIdx.x == SCAN_B - 1) bsum[blockIdx.x] = tmp[threadIdx.x];
}

__global__ void scan2_kernel(int* __restrict__ bsum, int nb) {
    __shared__ int tmp[128];
    int v = (threadIdx.x < nb) ? bsum[threadIdx.x] : 0;
    tmp[threadIdx.x] = v;
    __syncthreads();
    for (int off = 1; off < 128; off <<= 1) {
        int t = (threadIdx.x >= off) ? tmp[threadIdx.x - off] : 0;
        __syncthreads();
        tmp[threadIdx.x] += t;
        __syncthreads();
    }
    if (threadIdx.x < nb) bsum[threadIdx.x] = tmp[threadIdx.x] - v;  // exclusive
}

__global__ void scan3_kernel(int* __restrict__ out, const int* __restrict__ bsum, int n) {
    int i = blockIdx.x * SCAN_B + threadIdx.x;
    if (i < n) out[i] += bsum[blockIdx.x];
}

__global__ void set_total_kernel(int* __restrict__ row_ptr) {
    if (threadIdx.x == 0) row_ptr[NN] = ET;
}

__global__ void fill_edges_kernel(const int* __restrict__ src0, const int* __restrict__ dst0,
                                  const int* __restrict__ row_ptr, int* __restrict__ cursor,
                                  int* __restrict__ ssrc, int* __restrict__ pos) {
    int e = blockIdx.x * blockDim.x + threadIdx.x;
    if (e >= EE) return;
    int d = dst0[e];
    int p = atomicAdd(&cursor[d], 1);
    int idx = row_ptr[d] + p;
    ssrc[idx] = src0[e];
    pos[e] = idx;
}

__global__ void fill_loops_kernel(const int* __restrict__ row_ptr, int* __restrict__ cursor,
                                  int* __restrict__ ssrc, int* __restrict__ pos) {
    int n = blockIdx.x * blockDim.x + threadIdx.x;
    if (n >= NN) return;
    int p = atomicAdd(&cursor[n], 1);
    int idx = row_ptr[n] + p;
    ssrc[idx] = n;
    pos[EE + n] = idx;
}

// ------------------------------------------------------------- conversions

__global__ void convx_kernel(const float* __restrict__ x, unsigned short* __restrict__ xb) {
    int i = blockIdx.x * blockDim.x + threadIdx.x;
    if (i >= NPAD * 32) return;
    int row = i >> 5;
    float v = 0.f;
    if (row < NN) v = x[i];
    xb[i] = f2bf(v);
}

__global__ void convw_kernel(const float* __restrict__ W, unsigned short* __restrict__ Wt,
                             int K, int Nc) {
    int i = blockIdx.x * blockDim.x + threadIdx.x;
    if (i >= K * Nc) return;
    int c = i / K, k = i - c * K;
    Wt[i] = f2bf(W[(size_t)k * Nc + c]);
}

// ------------------------------------------------------------ bf16 MFMA GEMM
// C[NPAD,Nc] (bf16) = A[NPAD,K] (bf16) @ Bt[Nc,K]^T (bf16), fp32 accumulate.
// 128x128 tile, BK=32, 256 threads = 4 waves (2x2), each wave 64x64 (4x4 frags).

__global__ __launch_bounds__(256) void gemm_bf16_kernel(const unsigned short* __restrict__ A,
                                                        const unsigned short* __restrict__ Bt,
                                                        unsigned short* __restrict__ C,
                                                        int K, int Nc) {
    __shared__ unsigned short As[128][40];
    __shared__ unsigned short Bs[128][40];
    const int tid = threadIdx.x;
    const int bm = blockIdx.x * 128;
    const int bn = blockIdx.y * 128;
    const int lane = tid & 63;
    const int wv = tid >> 6;
    const int wrow = (wv >> 1) * 64;
    const int wcol = (wv & 1) * 64;
    const int lrow = tid >> 1;          // 0..127
    const int lseg = (tid & 1) * 16;    // 0 or 16
    const int l15 = lane & 15;
    const int kgrp = (lane >> 4) * 8;

    f32x4 acc[4][4];
#pragma unroll
    for (int m = 0; m < 4; m++)
#pragma unroll
        for (int n = 0; n < 4; n++) acc[m][n] = (f32x4)0.f;

    for (int k0 = 0; k0 < K; k0 += 32) {
        const unsigned short* ga = &A[(size_t)(bm + lrow) * K + k0 + lseg];
        const unsigned short* gb = &Bt[(size_t)(bn + lrow) * K + k0 + lseg];
        u16x8 a0 = *(const u16x8*)ga;
        u16x8 a1 = *(const u16x8*)(ga + 8);
        u16x8 b0 = *(const u16x8*)gb;
        u16x8 b1 = *(const u16x8*)(gb + 8);
        *(u16x8*)&As[lrow][lseg] = a0;
        *(u16x8*)&As[lrow][lseg + 8] = a1;
        *(u16x8*)&Bs[lrow][lseg] = b0;
        *(u16x8*)&Bs[lrow][lseg + 8] = b1;
        __syncthreads();
        bf16x8 af[4], bfr[4];
#pragma unroll
        for (int m = 0; m < 4; m++)
            af[m] = *(const bf16x8*)&As[wrow + m * 16 + l15][kgrp];
#pragma unroll
        for (int n = 0; n < 4; n++)
            bfr[n] = *(const bf16x8*)&Bs[wcol + n * 16 + l15][kgrp];
#pragma unroll
        for (int m = 0; m < 4; m++)
#pragma unroll
            for (int n = 0; n < 4; n++)
                acc[m][n] = __builtin_amdgcn_mfma_f32_16x16x32_bf16(af[m], bfr[n], acc[m][n], 0, 0, 0);
        __syncthreads();
    }
    // epilogue: D row = (lane>>4)*4 + j, col = lane&15  [m89-verified]
#pragma unroll
    for (int m = 0; m < 4; m++) {
#pragma unroll
        for (int n = 0; n < 4; n++) {
#pragma unroll
            for (int j = 0; j < 4; j++) {
                int row = bm + wrow + m * 16 + (lane >> 4) * 4 + j;
                int col = bn + wcol + n * 16 + l15;
                C[(size_t)row * Nc + col] = f2bf(acc[m][n][j]);
            }
        }
    }
}

// --------------------------------------------------- per-node attention dots

template <int C_>
__global__ __launch_bounds__(256) void attn_node_kernel(const unsigned short* __restrict__ xs,
                                                        const float* __restrict__ a_s,
                                                        const float* __restrict__ a_d,
                                                        float* __restrict__ al_s,
                                                        float* __restrict__ al_d) {
    constexpr int HC = HH * C_;
    constexpr int NK = HC / 64;
    int wid = (blockIdx.x * blockDim.x + threadIdx.x) >> 6;
    int lane = threadIdx.x & 63;
    if (wid >= NN) return;
    const unsigned short* row = xs + (size_t)wid * HC;
    float ss[HH] = {0.f, 0.f, 0.f, 0.f};
    float sd[HH] = {0.f, 0.f, 0.f, 0.f};
#pragma unroll
    for (int k = 0; k < NK; k++) {
        int idx = (k << 6) + lane;
        float v = bf2f(row[idx]);
        float ps = v * a_s[idx];
        float pd = v * a_d[idx];
#pragma unroll
        for (int off = 32; off; off >>= 1) {
            ps += __shfl_xor(ps, off);
            pd += __shfl_xor(pd, off);
        }
        ss[(k * 64) / C_] += ps;
        sd[(k * 64) / C_] += pd;
    }
    if (lane == 0) {
#pragma unroll
        for (int h = 0; h < HH; h++) {
            al_s[(size_t)wid * HH + h] = ss[h];
            al_d[(size_t)wid * HH + h] = sd[h];
        }
    }
}

// ------------------------------------------------------------- edge logits

__global__ void wea_kernel(const float* __restrict__ We, const float* __restrict__ ae,
                           float* __restrict__ Wea, int HC, int C) {
    int t = threadIdx.x;
    if (t >= 24) return;
    int k = t / 4, h = t % 4;
    float s = 0.f;
    for (int c = 0; c < C; c++) s += We[(size_t)k * HC + h * C + c] * ae[(size_t)h * C + c];
    Wea[k * 4 + h] = s;
}

__global__ void edge_al_kernel(const int* __restrict__ src0, const int* __restrict__ dst0,
                               const float* __restrict__ ef, const float* __restrict__ emean,
                               const float* __restrict__ Wea, const int* __restrict__ pos,
                               const float* __restrict__ al_s, const float* __restrict__ al_d,
                               float* __restrict__ al) {
    int e = blockIdx.x * blockDim.x + threadIdx.x;
    if (e >= ET) return;
    int s, d;
    float ev[6];
    if (e < EE) {
        s = src0[e];
        d = dst0[e];
#pragma unroll
        for (int k = 0; k < 6; k++) ev[k] = ef[(size_t)e * 6 + k];
    } else {
        s = d = e - EE;
#pragma unroll
        for (int k = 0; k < 6; k++) ev[k] = emean[(size_t)s * 6 + k];
    }
    float4 as4 = *(const float4*)&al_s[(size_t)s * 4];
    float4 ad4 = *(const float4*)&al_d[(size_t)d * 4];
    float asv[4] = {as4.x, as4.y, as4.z, as4.w};
    float adv[4] = {ad4.x, ad4.y, ad4.z, ad4.w};
    float o[4];
#pragma unroll
    for (int h = 0; h < 4; h++) {
        float v = asv[h] + adv[h];
#pragma unroll
        for (int k = 0; k < 6; k++) v += ev[k] * Wea[k * 4 + h];
        o[h] = v > 0.f ? v : 0.2f * v;
    }
    *(float4*)&al[(size_t)pos[e] * 4] = make_float4(o[0], o[1], o[2], o[3]);
}

// ---------------------- fused softmax + aggregation + bias + BN + ELU (wave/node)

template <int C_>
__global__ __launch_bounds__(256) void aggregate_kernel(const unsigned short* __restrict__ xs,
                                                        const float* __restrict__ al,
                                                        const int* __restrict__ rowptr,
                                                        const int* __restrict__ ssrc,
                                                        const float* __restrict__ bias,
                                                        const float* __restrict__ gam,
                                                        const float* __restrict__ bet,
                                                        unsigned short* __restrict__ hout) {
    constexpr int HC = HH * C_;
    constexpr int NP = HC / 128;
    int wid = (blockIdx.x * blockDim.x + threadIdx.x) >> 6;
    int lane = threadIdx.x & 63;
    if (wid >= NN) return;
    int b = rowptr[wid], e = rowptr[wid + 1];

    // pass 1: per-head max over this node's logits
    float m0 = -1e30f, m1 = -1e30f, m2 = -1e30f, m3 = -1e30f;
    for (int i = b + lane; i < e; i += 64) {
        float4 v = *(const float4*)&al[(size_t)i * 4];
        m0 = fmaxf(m0, v.x); m1 = fmaxf(m1, v.y);
        m2 = fmaxf(m2, v.z); m3 = fmaxf(m3, v.w);
    }
#pragma unroll
    for (int off = 32; off; off >>= 1) {
        m0 = fmaxf(m0, __shfl_xor(m0, off)); m1 = fmaxf(m1, __shfl_xor(m1, off));
        m2 = fmaxf(m2, __shfl_xor(m2, off)); m3 = fmaxf(m3, __shfl_xor(m3, off));
    }
    // pass 2: per-head sum of exp
    float s0 = 0.f, s1 = 0.f, s2 = 0.f, s3 = 0.f;
    for (int i = b + lane; i < e; i += 64) {
        float4 v = *(const float4*)&al[(size_t)i * 4];
        s0 += __expf(v.x - m0); s1 += __expf(v.y - m1);
        s2 += __expf(v.z - m2); s3 += __expf(v.w - m3);
    }
#pragma unroll
    for (int off = 32; off; off >>= 1) {
        s0 += __shfl_xor(s0, off); s1 += __shfl_xor(s1, off);
        s2 += __shfl_xor(s2, off); s3 += __shfl_xor(s3, off);
    }
    float r0 = 1.f / (s0 + 1e-16f), r1 = 1.f / (s1 + 1e-16f);
    float r2 = 1.f / (s2 + 1e-16f), r3 = 1.f / (s3 + 1e-16f);

    // gather: lane covers channels {p*128 + lane*2, +1}
    float acc[NP][2];
#pragma unroll
    for (int p = 0; p < NP; p++) { acc[p][0] = 0.f; acc[p][1] = 0.f; }
    for (int i = b; i < e; i++) {
        int s = ssrc[i];
        float4 v = *(const float4*)&al[(size_t)i * 4];
        float w0 = __expf(v.x - m0) * r0;
        float w1 = __expf(v.y - m1) * r1;
        float w2 = __expf(v.z - m2) * r2;
        float w3 = __expf(v.w - m3) * r3;
        const unsigned short* row = xs + (size_t)s * HC;
#pragma unroll
        for (int p = 0; p < NP; p++) {
            float wsel;
            if constexpr (C_ == 128) {
                wsel = (p == 0) ? w0 : (p == 1) ? w1 : (p == 2) ? w2 : w3;
            } else {  // C_ == 64: head = 2p + (lane>=32)
                wsel = (p == 0) ? ((lane < 32) ? w0 : w1) : ((lane < 32) ? w2 : w3);
            }
            unsigned int pk = *(const unsigned int*)&row[p * 128 + lane * 2];
            acc[p][0] += wsel * bf2f((unsigned short)(pk & 0xffffu));
            acc[p][1] += wsel * bf2f((unsigned short)(pk >> 16));
        }
    }
#pragma unroll
    for (int p = 0; p < NP; p++) {
        int idx = p * 128 + lane * 2;
        float2 bi = *(const float2*)&bias[idx];
        float2 ga = *(const float2*)&gam[idx];
        float2 be = *(const float2*)&bet[idx];
        float v0 = acc[p][0] + bi.x;
        float v1 = acc[p][1] + bi.y;
        v0 = ga.x * v0 * RSQ + be.x;
        v1 = ga.y * v1 * RSQ + be.y;
        v0 = v0 > 0.f ? v0 : (__expf(v0) - 1.0f);
        v1 = v1 > 0.f ? v1 : (__expf(v1) - 1.0f);
        unsigned int pk = (unsigned int)f2bf(v0) | ((unsigned int)f2bf(v1) << 16);
        *(unsigned int*)&hout[(size_t)wid * HC + idx] = pk;
    }
}

// ----------------------------------------------------------- pooling + head

__global__ void bounds_kernel(const int* __restrict__ batch, int* __restrict__ first,
                              int* __restrict__ last) {
    int n = blockIdx.x * blockDim.x + threadIdx.x;
    if (n >= NN) return;
    int b = batch[n];
    if (n == 0 || batch[n - 1] != b) first[b] = n;
    if (n == NN - 1 || batch[n + 1] != b) last[b] = n;
}

__global__ __launch_bounds__(256) void pool_kernel(const unsigned short* __restrict__ h3,
                                                   const int* __restrict__ batch,
                                                   float* __restrict__ pooled) {
    int c = threadIdx.x;
    int n0 = blockIdx.x * 256;
    int nend = min(n0 + 256, NN);
    float local = 0.f;
    int curg = batch[n0];
    for (int n = n0; n < nend; n++) {
        int g = batch[n];
        if (g != curg) {
            atomicAdd(&pooled[(size_t)curg * 256 + c], local);
            local = 0.f;
            curg = g;
        }
        local += bf2f(h3[(size_t)n * 256 + c]);
    }
    atomicAdd(&pooled[(size_t)curg * 256 + c], local);
}

__global__ void final_kernel(const float* __restrict__ pooled,
                             const int* __restrict__ first, const int* __restrict__ last,
                             const float* __restrict__ Wf1, const float* __restrict__ bf1,
                             const float* __restrict__ gf, const float* __restrict__ bbf,
                             const float* __restrict__ Wf2, const float* __restrict__ bf2,
                             float* __restrict__ out) {
    int g = blockIdx.x;
    int j = threadIdx.x;  // 32 threads
    __shared__ float hh[32];
    float c = fmaxf((float)(last[g] - first[g] + 1), 1.0f);
    float inv = 1.0f / c;
    float acc = bf1[j];
    for (int i = 0; i < 256; i++) acc += (pooled[(size_t)g * 256 + i] * inv) * Wf1[(size_t)i * 32 + j];
    float v = gf[j] * acc * RSQ + bbf[j];
    hh[j] = v > 0.f ? v : (__expf(v) - 1.0f);
    __syncthreads();
    if (j == 0) {
        float l0 = bf2[0], l1 = bf2[1];
        for (int i = 0; i < 32; i++) {
            l0 += hh[i] * Wf2[i * 2 + 0];
            l1 += hh[i] * Wf2[i * 2 + 1];
        }
        float mx = fmaxf(l0, l1);
        float lse = mx + logf(__expf(l0 - mx) + __expf(l1 - mx));
        out[g * 2 + 0] = l0 - lse;
        out[g * 2 + 1] = l1 - lse;
    }
}

// -------------------------------------------------------------------- launch

extern "C" void kernel_launch(void* const* d_in, const int* in_sizes, int n_in,
                              void* d_out, int out_size, void* d_ws, size_t ws_size,
                              hipStream_t stream) {
    (void)in_sizes; (void)n_in; (void)out_size; (void)ws_size;

    const float* x  = (const float*)d_in[0];
    const float* ef = (const float*)d_in[1];
    const float* W_[3]  = {(const float*)d_in[2],  (const float*)d_in[10], (const float*)d_in[18]};
    const float* We_[3] = {(const float*)d_in[3],  (const float*)d_in[11], (const float*)d_in[19]};
    const float* As_[3] = {(const float*)d_in[4],  (const float*)d_in[12], (const float*)d_in[20]};
    const float* Ad_[3] = {(const float*)d_in[5],  (const float*)d_in[13], (const float*)d_in[21]};
    const float* Ae_[3] = {(const float*)d_in[6],  (const float*)d_in[14], (const float*)d_in[22]};
    const float* Bi_[3] = {(const float*)d_in[7],  (const float*)d_in[15], (const float*)d_in[23]};
    const float* Ga_[3] = {(const float*)d_in[8],  (const float*)d_in[16], (const float*)d_in[24]};
    const float* Be_[3] = {(const float*)d_in[9],  (const float*)d_in[17], (const float*)d_in[25]};
    const float* Wf1 = (const float*)d_in[26];
    const float* bf1 = (const float*)d_in[27];
    const float* gf  = (const float*)d_in[28];
    const float* bbf = (const float*)d_in[29];
    const float* Wf2 = (const float*)d_in[30];
    const float* bf2 = (const float*)d_in[31];
    const int* eidx  = (const int*)d_in[32];
    const int* src0  = eidx;
    const int* dst0  = eidx + EE;
    const int* batch = (const int*)d_in[33];
    float* out = (float*)d_out;

    char* p = (char*)d_ws;
    unsigned short* B0 = (unsigned short*)carve(p, (size_t)NPAD * 512 * 2);
    unsigned short* B1 = (unsigned short*)carve(p, (size_t)NPAD * 512 * 2);
    unsigned short* B2 = (unsigned short*)carve(p, (size_t)NPAD * 512 * 2);
    unsigned short* Wt = (unsigned short*)carve(p, (size_t)512 * 512 * 2);
    float* al     = (float*)carve(p, (size_t)ET * 4 * 4);
    float* als    = (float*)carve(p, (size_t)NN * 4 * 4);
    float* ald    = (float*)carve(p, (size_t)NN * 4 * 4);
    float* emean  = (float*)carve(p, (size_t)NN * 6 * 4);
    float* wea    = (float*)carve(p, 256);
    float* pooled = (float*)carve(p, (size_t)GG * 256 * 4);
    int* first  = (int*)carve(p, (size_t)GG * 4);
    int* last   = (int*)carve(p, (size_t)GG * 4);
    int* deg    = (int*)carve(p, (size_t)NN * 4);
    int* rowptr = (int*)carve(p, (size_t)(NN + 1) * 4);
    int* cursor = (int*)carve(p, (size_t)NN * 4);
    int* ssrc   = (int*)carve(p, (size_t)ET * 4);
    int* pos    = (int*)carve(p, (size_t)ET * 4);
    int* bsum   = (int*)carve(p, 512);

    hipMemsetAsync(deg, 0, (size_t)NN * 4, stream);
    hipMemsetAsync(emean, 0, (size_t)NN * 6 * 4, stream);
    hipMemsetAsync(cursor, 0, (size_t)NN * 4, stream);
    hipMemsetAsync(pooled, 0, (size_t)GG * 256 * 4, stream);
    hipMemsetAsync(first, 0x00, (size_t)GG * 4, stream);
    hipMemsetAsync(last, 0xFF, (size_t)GG * 4, stream);

    edge_accum_kernel<<<(EE + 255) / 256, 256, 0, stream>>>(dst0, ef, deg, emean);
    emean_kernel<<<(NN + 255) / 256, 256, 0, stream>>>(deg, emean);

    int nb = (NN + SCAN_B - 1) / SCAN_B;  // 98
    scan1_kernel<<<nb, SCAN_B, 0, stream>>>(deg, rowptr, bsum, NN);
    scan2_kernel<<<1, 128, 0, stream>>>(bsum, nb);
    scan3_kernel<<<nb, SCAN_B, 0, stream>>>(rowptr, bsum, NN);
    set_total_kernel<<<1, 64, 0, stream>>>(rowptr);
    fill_edges_kernel<<<(EE + 255) / 256, 256, 0, stream>>>(src0, dst0, rowptr, cursor, ssrc, pos);
    fill_loops_kernel<<<(NN + 255) / 256, 256, 0, stream>>>(rowptr, cursor, ssrc, pos);

    convx_kernel<<<(NPAD * 32 + 255) / 256, 256, 0, stream>>>(x, B0);

    const int fin[3] = {32, 256, 512};
    const int HCs[3] = {256, 512, 256};
    const int Cs[3]  = {64, 128, 64};
    const unsigned short* inb[3]  = {B0, B2, B0};
    unsigned short* outb[3]       = {B2, B0, B2};

    int wblocks = (NN * 64 + 255) / 256;
    for (int li = 0; li < 3; li++) {
        int K = fin[li], HC = HCs[li];
        convw_kernel<<<(K * HC + 255) / 256, 256, 0, stream>>>(W_[li], Wt, K, HC);
        dim3 gg(NPAD / 128, HC / 128);
        gemm_bf16_kernel<<<gg, 256, 0, stream>>>(inb[li], Wt, B1, K, HC);

        if (Cs[li] == 64)
            attn_node_kernel<64><<<wblocks, 256, 0, stream>>>(B1, As_[li], Ad_[li], als, ald);
        else
            attn_node_kernel<128><<<wblocks, 256, 0, stream>>>(B1, As_[li], Ad_[li], als, ald);

        wea_kernel<<<1, 32, 0, stream>>>(We_[li], Ae_[li], wea, HC, Cs[li]);
        edge_al_kernel<<<(ET + 255) / 256, 256, 0, stream>>>(src0, dst0, ef, emean, wea, pos,
                                                             als, ald, al);
        if (Cs[li] == 64)
            aggregate_kernel<64><<<wblocks, 256, 0, stream>>>(B1, al, rowptr, ssrc,
                                                              Bi_[li], Ga_[li], Be_[li], outb[li]);
        else
            aggregate_kernel<128><<<wblocks, 256, 0, stream>>>(B1, al, rowptr, ssrc,
                                                               Bi_[li], Ga_[li], Be_[li], outb[li]);
    }

    bounds_kernel<<<(NN + 255) / 256, 256, 0, stream>>>(batch, first, last);
    pool_kernel<<<(NN + 255) / 256, 256, 0, stream>>>(B2, batch, pooled);
    final_kernel<<<GG, 32, 0, stream>>>(pooled, first, last, Wf1, bf1, gf, bbf, Wf2, bf2, out);
}

// Round 3
// 837.048 us; speedup vs baseline: 2.4403x; 1.2529x over previous
//
#include <hip/hip_runtime.h>
#include <cstdint>
#include <cstddef>

#define NN 50000
#define NPAD 50048            // 391 * 128
#define EE 800000
#define ET (EE + NN)
#define GG 64
#define HH 4
#define RSQ 0.9999950000374997f   // 1/sqrt(1+1e-5)

typedef short bf16x8 __attribute__((ext_vector_type(8)));
typedef unsigned short u16x8 __attribute__((ext_vector_type(8)));
typedef float f32x4 __attribute__((ext_vector_type(4)));

__device__ __forceinline__ float bf2f(unsigned short u) {
    union { unsigned int i; float f; } v; v.i = ((unsigned int)u) << 16; return v.f;
}
__device__ __forceinline__ unsigned short f2bf(float f) {
    union { float f; unsigned int i; } v; v.f = f;
    unsigned int u = v.i;
    u += 0x7fffu + ((u >> 16) & 1u);
    return (unsigned short)(u >> 16);
}

static inline void* carve(char*& p, size_t bytes) {
    void* r = (void*)p;
    p += (bytes + 255) & ~(size_t)255;
    return r;
}

// ------------------------------------------------------------- CSR building

__global__ void deg_kernel(const int* __restrict__ dst0, int* __restrict__ deg) {
    int e = blockIdx.x * blockDim.x + threadIdx.x;
    if (e >= EE) return;
    atomicAdd(&deg[dst0[e]], 1);
}

#define SCAN_B 512
__global__ void scan1_kernel(const int* __restrict__ deg, int* __restrict__ out,
                             int* __restrict__ bsum, int n) {
    __shared__ int tmp[SCAN_B];
    int i = blockIdx.x * SCAN_B + threadIdx.x;
    int v = (i < n) ? (deg[i] + 1) : 0;   // +1 self loop
    tmp[threadIdx.x] = v;
    __syncthreads();
    for (int off = 1; off < SCAN_B; off <<= 1) {
        int t = (threadIdx.x >= off) ? tmp[threadIdx.x - off] : 0;
        __syncthreads();
        tmp[threadIdx.x] += t;
        __syncthreads();
    }
    if (i < n) out[i] = tmp[threadIdx.x] - v;       // exclusive
    if (threadIdx.x == SCAN_B - 1) bsum[blockIdx.x] = tmp[threadIdx.x];
}

__global__ void scan2_kernel(int* __restrict__ bsum, int nb) {
    __shared__ int tmp[128];
    int v = (threadIdx.x < nb) ? bsum[threadIdx.x] : 0;
    tmp[threadIdx.x] = v;
    __syncthreads();
    for (int off = 1; off < 128; off <<= 1) {
        int t = (threadIdx.x >= off) ? tmp[threadIdx.x - off] : 0;
        __syncthreads();
        tmp[threadIdx.x] += t;
        __syncthreads();
    }
    if (threadIdx.x < nb) bsum[threadIdx.x] = tmp[threadIdx.x] - v;  // exclusive
}

__global__ void scan3_kernel(int* __restrict__ out, const int* __restrict__ bsum, int n) {
    int i = blockIdx.x * SCAN_B + threadIdx.x;
    if (i < n) out[i] += bsum[blockIdx.x];
}

__global__ void set_total_kernel(int* __restrict__ row_ptr) {
    if (threadIdx.x == 0) row_ptr[NN] = ET;
}

__global__ void fill_edges_kernel(const int* __restrict__ src0, const int* __restrict__ dst0,
                                  const int* __restrict__ row_ptr, int* __restrict__ cursor,
                                  int* __restrict__ ssrc, int* __restrict__ seid,
                                  int* __restrict__ pos) {
    int e = blockIdx.x * blockDim.x + threadIdx.x;
    if (e >= EE) return;
    int d = dst0[e];
    int p = atomicAdd(&cursor[d], 1);
    int idx = row_ptr[d] + p;
    ssrc[idx] = src0[e];
    seid[idx] = e;
    pos[e] = idx;
}

__global__ void fill_loops_kernel(const int* __restrict__ row_ptr, int* __restrict__ cursor,
                                  int* __restrict__ ssrc, int* __restrict__ seid,
                                  int* __restrict__ pos) {
    int n = blockIdx.x * blockDim.x + threadIdx.x;
    if (n >= NN) return;
    int p = atomicAdd(&cursor[n], 1);
    int idx = row_ptr[n] + p;
    ssrc[idx] = n;
    seid[idx] = EE + n;
    pos[EE + n] = idx;
}

// emean via CSR segmented sum — no atomics. Wave per node, lanes over edges.
__global__ __launch_bounds__(256) void emean_csr_kernel(const int* __restrict__ rowptr,
                                                        const int* __restrict__ seid,
                                                        const float* __restrict__ ef,
                                                        float* __restrict__ emean) {
    int wid = (blockIdx.x * blockDim.x + threadIdx.x) >> 6;
    int lane = threadIdx.x & 63;
    if (wid >= NN) return;
    int b = rowptr[wid], e = rowptr[wid + 1];
    float s[6] = {0.f, 0.f, 0.f, 0.f, 0.f, 0.f};
    for (int i = b + lane; i < e; i += 64) {
        int eid = seid[i];
        if (eid < EE) {
            const float* row = &ef[(size_t)eid * 6];
#pragma unroll
            for (int k = 0; k < 6; k++) s[k] += row[k];
        }
    }
#pragma unroll
    for (int off = 32; off; off >>= 1)
#pragma unroll
        for (int k = 0; k < 6; k++) s[k] += __shfl_xor(s[k], off);
    if (lane == 0) {
        float inv = 1.0f / fmaxf((float)(e - b - 1), 1.0f);
#pragma unroll
        for (int k = 0; k < 6; k++) emean[(size_t)wid * 6 + k] = s[k] * inv;
    }
}

// ------------------------------------------------------------- conversions

__global__ void convx_kernel(const float* __restrict__ x, unsigned short* __restrict__ xb) {
    int i = blockIdx.x * blockDim.x + threadIdx.x;
    if (i >= NPAD * 32) return;
    int row = i >> 5;
    float v = 0.f;
    if (row < NN) v = x[i];
    xb[i] = f2bf(v);
}

__global__ void convw_kernel(const float* __restrict__ W, unsigned short* __restrict__ Wt,
                             int K, int Nc) {
    int i = blockIdx.x * blockDim.x + threadIdx.x;
    if (i >= K * Nc) return;
    int c = i / K, k = i - c * K;
    Wt[i] = f2bf(W[(size_t)k * Nc + c]);
}

// ------------------------------------------------------------ bf16 MFMA GEMM
// C[NPAD,Nc] (bf16) = A[NPAD,K] (bf16) @ Bt[Nc,K]^T (bf16), fp32 accumulate.
// 128x128 tile, BK=32, 256 threads = 4 waves (2x2), each wave 64x64 (4x4 frags).

__global__ __launch_bounds__(256) void gemm_bf16_kernel(const unsigned short* __restrict__ A,
                                                        const unsigned short* __restrict__ Bt,
                                                        unsigned short* __restrict__ C,
                                                        int K, int Nc) {
    __shared__ unsigned short As[128][40];
    __shared__ unsigned short Bs[128][40];
    const int tid = threadIdx.x;
    const int bm = blockIdx.x * 128;
    const int bn = blockIdx.y * 128;
    const int lane = tid & 63;
    const int wv = tid >> 6;
    const int wrow = (wv >> 1) * 64;
    const int wcol = (wv & 1) * 64;
    const int lrow = tid >> 1;          // 0..127
    const int lseg = (tid & 1) * 16;    // 0 or 16
    const int l15 = lane & 15;
    const int kgrp = (lane >> 4) * 8;

    f32x4 acc[4][4];
#pragma unroll
    for (int m = 0; m < 4; m++)
#pragma unroll
        for (int n = 0; n < 4; n++) acc[m][n] = (f32x4)0.f;

    for (int k0 = 0; k0 < K; k0 += 32) {
        const unsigned short* ga = &A[(size_t)(bm + lrow) * K + k0 + lseg];
        const unsigned short* gb = &Bt[(size_t)(bn + lrow) * K + k0 + lseg];
        u16x8 a0 = *(const u16x8*)ga;
        u16x8 a1 = *(const u16x8*)(ga + 8);
        u16x8 b0 = *(const u16x8*)gb;
        u16x8 b1 = *(const u16x8*)(gb + 8);
        *(u16x8*)&As[lrow][lseg] = a0;
        *(u16x8*)&As[lrow][lseg + 8] = a1;
        *(u16x8*)&Bs[lrow][lseg] = b0;
        *(u16x8*)&Bs[lrow][lseg + 8] = b1;
        __syncthreads();
        bf16x8 af[4], bfr[4];
#pragma unroll
        for (int m = 0; m < 4; m++)
            af[m] = *(const bf16x8*)&As[wrow + m * 16 + l15][kgrp];
#pragma unroll
        for (int n = 0; n < 4; n++)
            bfr[n] = *(const bf16x8*)&Bs[wcol + n * 16 + l15][kgrp];
#pragma unroll
        for (int m = 0; m < 4; m++)
#pragma unroll
            for (int n = 0; n < 4; n++)
                acc[m][n] = __builtin_amdgcn_mfma_f32_16x16x32_bf16(af[m], bfr[n], acc[m][n], 0, 0, 0);
        __syncthreads();
    }
    // epilogue: D row = (lane>>4)*4 + j, col = lane&15  [m89-verified]
#pragma unroll
    for (int m = 0; m < 4; m++) {
#pragma unroll
        for (int n = 0; n < 4; n++) {
#pragma unroll
            for (int j = 0; j < 4; j++) {
                int row = bm + wrow + m * 16 + (lane >> 4) * 4 + j;
                int col = bn + wcol + n * 16 + l15;
                C[(size_t)row * Nc + col] = f2bf(acc[m][n][j]);
            }
        }
    }
}

// --------------------------------------------------- per-node attention dots

template <int C_>
__global__ __launch_bounds__(256) void attn_node_kernel(const unsigned short* __restrict__ xs,
                                                        const float* __restrict__ a_s,
                                                        const float* __restrict__ a_d,
                                                        float* __restrict__ al_s,
                                                        float* __restrict__ al_d) {
    constexpr int HC = HH * C_;
    constexpr int NK = HC / 64;
    int wid = (blockIdx.x * blockDim.x + threadIdx.x) >> 6;
    int lane = threadIdx.x & 63;
    if (wid >= NN) return;
    const unsigned short* row = xs + (size_t)wid * HC;
    float ss[HH] = {0.f, 0.f, 0.f, 0.f};
    float sd[HH] = {0.f, 0.f, 0.f, 0.f};
#pragma unroll
    for (int k = 0; k < NK; k++) {
        int idx = (k << 6) + lane;
        float v = bf2f(row[idx]);
        float ps = v * a_s[idx];
        float pd = v * a_d[idx];
#pragma unroll
        for (int off = 32; off; off >>= 1) {
            ps += __shfl_xor(ps, off);
            pd += __shfl_xor(pd, off);
        }
        ss[(k * 64) / C_] += ps;
        sd[(k * 64) / C_] += pd;
    }
    if (lane == 0) {
#pragma unroll
        for (int h = 0; h < HH; h++) {
            al_s[(size_t)wid * HH + h] = ss[h];
            al_d[(size_t)wid * HH + h] = sd[h];
        }
    }
}

// ------------------------------------------------------------- edge logits

__global__ void wea_kernel(const float* __restrict__ We, const float* __restrict__ ae,
                           float* __restrict__ Wea, int HC, int C) {
    int t = threadIdx.x;
    if (t >= 24) return;
    int k = t / 4, h = t % 4;
    float s = 0.f;
    for (int c = 0; c < C; c++) s += We[(size_t)k * HC + h * C + c] * ae[(size_t)h * C + c];
    Wea[k * 4 + h] = s;
}

__global__ void edge_al_kernel(const int* __restrict__ src0, const int* __restrict__ dst0,
                               const float* __restrict__ ef, const float* __restrict__ emean,
                               const float* __restrict__ Wea, const int* __restrict__ pos,
                               const float* __restrict__ al_s, const float* __restrict__ al_d,
                               float* __restrict__ al) {
    int e = blockIdx.x * blockDim.x + threadIdx.x;
    if (e >= ET) return;
    int s, d;
    float ev[6];
    if (e < EE) {
        s = src0[e];
        d = dst0[e];
#pragma unroll
        for (int k = 0; k < 6; k++) ev[k] = ef[(size_t)e * 6 + k];
    } else {
        s = d = e - EE;
#pragma unroll
        for (int k = 0; k < 6; k++) ev[k] = emean[(size_t)s * 6 + k];
    }
    float4 as4 = *(const float4*)&al_s[(size_t)s * 4];
    float4 ad4 = *(const float4*)&al_d[(size_t)d * 4];
    float asv[4] = {as4.x, as4.y, as4.z, as4.w};
    float adv[4] = {ad4.x, ad4.y, ad4.z, ad4.w};
    float o[4];
#pragma unroll
    for (int h = 0; h < 4; h++) {
        float v = asv[h] + adv[h];
#pragma unroll
        for (int k = 0; k < 6; k++) v += ev[k] * Wea[k * 4 + h];
        o[h] = v > 0.f ? v : 0.2f * v;
    }
    *(float4*)&al[(size_t)pos[e] * 4] = make_float4(o[0], o[1], o[2], o[3]);
}

// ---------------------- fused softmax + aggregation + bias + BN + ELU (wave/node)

template <int C_>
__global__ __launch_bounds__(256) void aggregate_kernel(const unsigned short* __restrict__ xs,
                                                        const float* __restrict__ al,
                                                        const int* __restrict__ rowptr,
                                                        const int* __restrict__ ssrc,
                                                        const float* __restrict__ bias,
                                                        const float* __restrict__ gam,
                                                        const float* __restrict__ bet,
                                                        unsigned short* __restrict__ hout) {
    constexpr int HC = HH * C_;
    constexpr int NP = HC / 128;
    int wid = (blockIdx.x * blockDim.x + threadIdx.x) >> 6;
    int lane = threadIdx.x & 63;
    if (wid >= NN) return;
    int b = rowptr[wid], e = rowptr[wid + 1];

    // pass 1: per-head max over this node's logits
    float m0 = -1e30f, m1 = -1e30f, m2 = -1e30f, m3 = -1e30f;
    for (int i = b + lane; i < e; i += 64) {
        float4 v = *(const float4*)&al[(size_t)i * 4];
        m0 = fmaxf(m0, v.x); m1 = fmaxf(m1, v.y);
        m2 = fmaxf(m2, v.z); m3 = fmaxf(m3, v.w);
    }
#pragma unroll
    for (int off = 32; off; off >>= 1) {
        m0 = fmaxf(m0, __shfl_xor(m0, off)); m1 = fmaxf(m1, __shfl_xor(m1, off));
        m2 = fmaxf(m2, __shfl_xor(m2, off)); m3 = fmaxf(m3, __shfl_xor(m3, off));
    }
    // pass 2: per-head sum of exp
    float s0 = 0.f, s1 = 0.f, s2 = 0.f, s3 = 0.f;
    for (int i = b + lane; i < e; i += 64) {
        float4 v = *(const float4*)&al[(size_t)i * 4];
        s0 += __expf(v.x - m0); s1 += __expf(v.y - m1);
        s2 += __expf(v.z - m2); s3 += __expf(v.w - m3);
    }
#pragma unroll
    for (int off = 32; off; off >>= 1) {
        s0 += __shfl_xor(s0, off); s1 += __shfl_xor(s1, off);
        s2 += __shfl_xor(s2, off); s3 += __shfl_xor(s3, off);
    }
    float r0 = 1.f / (s0 + 1e-16f), r1 = 1.f / (s1 + 1e-16f);
    float r2 = 1.f / (s2 + 1e-16f), r3 = 1.f / (s3 + 1e-16f);

    // gather: lane covers channels {p*128 + lane*2, +1}
    float acc[NP][2];
#pragma unroll
    for (int p = 0; p < NP; p++) { acc[p][0] = 0.f; acc[p][1] = 0.f; }
    for (int i = b; i < e; i++) {
        int s = ssrc[i];
        float4 v = *(const float4*)&al[(size_t)i * 4];
        float w0 = __expf(v.x - m0) * r0;
        float w1 = __expf(v.y - m1) * r1;
        float w2 = __expf(v.z - m2) * r2;
        float w3 = __expf(v.w - m3) * r3;
        const unsigned short* row = xs + (size_t)s * HC;
#pragma unroll
        for (int p = 0; p < NP; p++) {
            float wsel;
            if constexpr (C_ == 128) {
                wsel = (p == 0) ? w0 : (p == 1) ? w1 : (p == 2) ? w2 : w3;
            } else {  // C_ == 64: head = 2p + (lane>=32)
                wsel = (p == 0) ? ((lane < 32) ? w0 : w1) : ((lane < 32) ? w2 : w3);
            }
            unsigned int pk = *(const unsigned int*)&row[p * 128 + lane * 2];
            acc[p][0] += wsel * bf2f((unsigned short)(pk & 0xffffu));
            acc[p][1] += wsel * bf2f((unsigned short)(pk >> 16));
        }
    }
#pragma unroll
    for (int p = 0; p < NP; p++) {
        int idx = p * 128 + lane * 2;
        float2 bi = *(const float2*)&bias[idx];
        float2 ga = *(const float2*)&gam[idx];
        float2 be = *(const float2*)&bet[idx];
        float v0 = acc[p][0] + bi.x;
        float v1 = acc[p][1] + bi.y;
        v0 = ga.x * v0 * RSQ + be.x;
        v1 = ga.y * v1 * RSQ + be.y;
        v0 = v0 > 0.f ? v0 : (__expf(v0) - 1.0f);
        v1 = v1 > 0.f ? v1 : (__expf(v1) - 1.0f);
        unsigned int pk = (unsigned int)f2bf(v0) | ((unsigned int)f2bf(v1) << 16);
        *(unsigned int*)&hout[(size_t)wid * HC + idx] = pk;
    }
}

// ----------------------------------------------------------- pooling + head

__global__ void bounds_kernel(const int* __restrict__ batch, int* __restrict__ first,
                              int* __restrict__ last) {
    int n = blockIdx.x * blockDim.x + threadIdx.x;
    if (n >= NN) return;
    int b = batch[n];
    if (n == 0 || batch[n - 1] != b) first[b] = n;
    if (n == NN - 1 || batch[n + 1] != b) last[b] = n;
}

__global__ __launch_bounds__(256) void pool_kernel(const unsigned short* __restrict__ h3,
                                                   const int* __restrict__ batch,
                                                   float* __restrict__ pooled) {
    int c = threadIdx.x;
    int n0 = blockIdx.x * 256;
    int nend = min(n0 + 256, NN);
    float local = 0.f;
    int curg = batch[n0];
    for (int n = n0; n < nend; n++) {
        int g = batch[n];
        if (g != curg) {
            atomicAdd(&pooled[(size_t)curg * 256 + c], local);
            local = 0.f;
            curg = g;
        }
        local += bf2f(h3[(size_t)n * 256 + c]);
    }
    atomicAdd(&pooled[(size_t)curg * 256 + c], local);
}

__global__ void final_kernel(const float* __restrict__ pooled,
                             const int* __restrict__ first, const int* __restrict__ last,
                             const float* __restrict__ Wf1, const float* __restrict__ bf1,
                             const float* __restrict__ gf, const float* __restrict__ bbf,
                             const float* __restrict__ Wf2, const float* __restrict__ bf2,
                             float* __restrict__ out) {
    int g = blockIdx.x;
    int j = threadIdx.x;  // 32 threads
    __shared__ float hh[32];
    float c = fmaxf((float)(last[g] - first[g] + 1), 1.0f);
    float inv = 1.0f / c;
    float acc = bf1[j];
    for (int i = 0; i < 256; i++) acc += (pooled[(size_t)g * 256 + i] * inv) * Wf1[(size_t)i * 32 + j];
    float v = gf[j] * acc * RSQ + bbf[j];
    hh[j] = v > 0.f ? v : (__expf(v) - 1.0f);
    __syncthreads();
    if (j == 0) {
        float l0 = bf2[0], l1 = bf2[1];
        for (int i = 0; i < 32; i++) {
            l0 += hh[i] * Wf2[i * 2 + 0];
            l1 += hh[i] * Wf2[i * 2 + 1];
        }
        float mx = fmaxf(l0, l1);
        float lse = mx + logf(__expf(l0 - mx) + __expf(l1 - mx));
        out[g * 2 + 0] = l0 - lse;
        out[g * 2 + 1] = l1 - lse;
    }
}

// -------------------------------------------------------------------- launch

extern "C" void kernel_launch(void* const* d_in, const int* in_sizes, int n_in,
                              void* d_out, int out_size, void* d_ws, size_t ws_size,
                              hipStream_t stream) {
    (void)in_sizes; (void)n_in; (void)out_size; (void)ws_size;

    const float* x  = (const float*)d_in[0];
    const float* ef = (const float*)d_in[1];
    const float* W_[3]  = {(const float*)d_in[2],  (const float*)d_in[10], (const float*)d_in[18]};
    const float* We_[3] = {(const float*)d_in[3],  (const float*)d_in[11], (const float*)d_in[19]};
    const float* As_[3] = {(const float*)d_in[4],  (const float*)d_in[12], (const float*)d_in[20]};
    const float* Ad_[3] = {(const float*)d_in[5],  (const float*)d_in[13], (const float*)d_in[21]};
    const float* Ae_[3] = {(const float*)d_in[6],  (const float*)d_in[14], (const float*)d_in[22]};
    const float* Bi_[3] = {(const float*)d_in[7],  (const float*)d_in[15], (const float*)d_in[23]};
    const float* Ga_[3] = {(const float*)d_in[8],  (const float*)d_in[16], (const float*)d_in[24]};
    const float* Be_[3] = {(const float*)d_in[9],  (const float*)d_in[17], (const float*)d_in[25]};
    const float* Wf1 = (const float*)d_in[26];
    const float* bf1 = (const float*)d_in[27];
    const float* gf  = (const float*)d_in[28];
    const float* bbf = (const float*)d_in[29];
    const float* Wf2 = (const float*)d_in[30];
    const float* bf2 = (const float*)d_in[31];
    const int* eidx  = (const int*)d_in[32];
    const int* src0  = eidx;
    const int* dst0  = eidx + EE;
    const int* batch = (const int*)d_in[33];
    float* out = (float*)d_out;

    char* p = (char*)d_ws;
    unsigned short* B0 = (unsigned short*)carve(p, (size_t)NPAD * 512 * 2);
    unsigned short* B1 = (unsigned short*)carve(p, (size_t)NPAD * 512 * 2);
    unsigned short* B2 = (unsigned short*)carve(p, (size_t)NPAD * 512 * 2);
    unsigned short* Wt = (unsigned short*)carve(p, (size_t)512 * 512 * 2);
    float* al     = (float*)carve(p, (size_t)ET * 4 * 4);
    float* als    = (float*)carve(p, (size_t)NN * 4 * 4);
    float* ald    = (float*)carve(p, (size_t)NN * 4 * 4);
    float* emean  = (float*)carve(p, (size_t)NN * 6 * 4);
    float* wea    = (float*)carve(p, 256);
    float* pooled = (float*)carve(p, (size_t)GG * 256 * 4);
    int* first  = (int*)carve(p, (size_t)GG * 4);
    int* last   = (int*)carve(p, (size_t)GG * 4);
    int* deg    = (int*)carve(p, (size_t)NN * 4);
    int* rowptr = (int*)carve(p, (size_t)(NN + 1) * 4);
    int* cursor = (int*)carve(p, (size_t)NN * 4);
    int* ssrc   = (int*)carve(p, (size_t)ET * 4);
    int* seid   = (int*)carve(p, (size_t)ET * 4);
    int* pos    = (int*)carve(p, (size_t)ET * 4);
    int* bsum   = (int*)carve(p, 512);

    hipMemsetAsync(deg, 0, (size_t)NN * 4, stream);
    hipMemsetAsync(cursor, 0, (size_t)NN * 4, stream);
    hipMemsetAsync(pooled, 0, (size_t)GG * 256 * 4, stream);
    hipMemsetAsync(first, 0x00, (size_t)GG * 4, stream);
    hipMemsetAsync(last, 0xFF, (size_t)GG * 4, stream);

    deg_kernel<<<(EE + 255) / 256, 256, 0, stream>>>(dst0, deg);

    int nb = (NN + SCAN_B - 1) / SCAN_B;  // 98
    scan1_kernel<<<nb, SCAN_B, 0, stream>>>(deg, rowptr, bsum, NN);
    scan2_kernel<<<1, 128, 0, stream>>>(bsum, nb);
    scan3_kernel<<<nb, SCAN_B, 0, stream>>>(rowptr, bsum, NN);
    set_total_kernel<<<1, 64, 0, stream>>>(rowptr);
    fill_edges_kernel<<<(EE + 255) / 256, 256, 0, stream>>>(src0, dst0, rowptr, cursor,
                                                            ssrc, seid, pos);
    fill_loops_kernel<<<(NN + 255) / 256, 256, 0, stream>>>(rowptr, cursor, ssrc, seid, pos);

    int wblocks = (NN * 64 + 255) / 256;
    emean_csr_kernel<<<wblocks, 256, 0, stream>>>(rowptr, seid, ef, emean);

    convx_kernel<<<(NPAD * 32 + 255) / 256, 256, 0, stream>>>(x, B0);

    const int fin[3] = {32, 256, 512};
    const int HCs[3] = {256, 512, 256};
    const int Cs[3]  = {64, 128, 64};
    const unsigned short* inb[3]  = {B0, B2, B0};
    unsigned short* outb[3]       = {B2, B0, B2};

    for (int li = 0; li < 3; li++) {
        int K = fin[li], HC = HCs[li];
        convw_kernel<<<(K * HC + 255) / 256, 256, 0, stream>>>(W_[li], Wt, K, HC);
        dim3 gg(NPAD / 128, HC / 128);
        gemm_bf16_kernel<<<gg, 256, 0, stream>>>(inb[li], Wt, B1, K, HC);

        if (Cs[li] == 64)
            attn_node_kernel<64><<<wblocks, 256, 0, stream>>>(B1, As_[li], Ad_[li], als, ald);
        else
            attn_node_kernel<128><<<wblocks, 256, 0, stream>>>(B1, As_[li], Ad_[li], als, ald);

        wea_kernel<<<1, 32, 0, stream>>>(We_[li], Ae_[li], wea, HC, Cs[li]);
        edge_al_kernel<<<(ET + 255) / 256, 256, 0, stream>>>(src0, dst0, ef, emean, wea, pos,
                                                             als, ald, al);
        if (Cs[li] == 64)
            aggregate_kernel<64><<<wblocks, 256, 0, stream>>>(B1, al, rowptr, ssrc,
                                                              Bi_[li], Ga_[li], Be_[li], outb[li]);
        else
            aggregate_kernel<128><<<wblocks, 256, 0, stream>>>(B1, al, rowptr, ssrc,
                                                               Bi_[li], Ga_[li], Be_[li], outb[li]);
    }

    bounds_kernel<<<(NN + 255) / 256, 256, 0, stream>>>(batch, first, last);
    pool_kernel<<<(NN + 255) / 256, 256, 0, stream>>>(B2, batch, pooled);
    final_kernel<<<GG, 32, 0, stream>>>(pooled, first, last, Wf1, bf1, gf, bbf, Wf2, bf2, out);
}